// Round 2
// 417.147 us; speedup vs baseline: 1.0206x; 1.0206x over previous
//
#include <hip/hip_runtime.h>

// ChessboardLayer: space-to-depth into 8x8 cell grid.
// Input  (B=32, H=256, W=256, C=32) fp32, NHWC contiguous.
// Output (B, 8, 8, 32768) fp32.
//
// The whole op is a permutation of 65536 contiguous 4 KiB blocks:
//   out block: blk = ((b*8 + i)*8 + j)*32 + r      (r = h2, row within cell)
//   in  block: (b*256 + i*32 + r)*8 + j
//
// v3 (= v2 + compile fix): persistent grid-stride blocks, 4 output blocks
// (16 KiB) per WG iteration, 4 independent 16B load/store pairs per thread
// (ILP=4), nontemporal hints (pure streaming, no reuse).
// __builtin_nontemporal_* requires a NATIVE vector type, not HIP's
// float4 struct -> use ext_vector_type(4).

typedef float f32x4 __attribute__((ext_vector_type(4)));

__global__ __launch_bounds__(256) void chessboard_kernel(
    const f32x4* __restrict__ in, f32x4* __restrict__ out) {
    const unsigned t = threadIdx.x;
    for (unsigned gq = blockIdx.x; gq < 16384u; gq += gridDim.x) {
        unsigned r0 = (gq & 7u) * 4u;
        unsigned j  = (gq >> 3) & 7u;
        unsigned i  = (gq >> 6) & 7u;
        unsigned b  = gq >> 9;

        // float4 index of (b, h=i*32+r0, w=j*32, c=0), plus this lane's slot
        unsigned in_base  = ((b * 256u + i * 32u + r0) * 8u + j) * 256u + t;
        unsigned out_base = gq * 1024u + t;

        // 4 independent 16B loads (input blocks 2048 float4 apart), then
        // 4 independent 16B stores (output blocks 256 float4 apart).
        f32x4 v0 = __builtin_nontemporal_load(&in[in_base]);
        f32x4 v1 = __builtin_nontemporal_load(&in[in_base + 2048u]);
        f32x4 v2 = __builtin_nontemporal_load(&in[in_base + 4096u]);
        f32x4 v3 = __builtin_nontemporal_load(&in[in_base + 6144u]);

        __builtin_nontemporal_store(v0, &out[out_base]);
        __builtin_nontemporal_store(v1, &out[out_base + 256u]);
        __builtin_nontemporal_store(v2, &out[out_base + 512u]);
        __builtin_nontemporal_store(v3, &out[out_base + 768u]);
    }
}

extern "C" void kernel_launch(void* const* d_in, const int* in_sizes, int n_in,
                              void* d_out, int out_size, void* d_ws, size_t ws_size,
                              hipStream_t stream) {
    const f32x4* in  = (const f32x4*)d_in[0];
    f32x4*       out = (f32x4*)d_out;
    // 16384 groups of 4 blocks; 2048 persistent WGs (8/CU, 32 waves/CU),
    // each WG runs 8 grid-stride iterations.
    chessboard_kernel<<<2048, 256, 0, stream>>>(in, out);
}